// Round 5
// baseline (411.129 us; speedup 1.0000x reference)
//
#include <hip/hip_runtime.h>
#include <hip/hip_bf16.h>

// Problem constants
constexpr int Bn = 8, Sn = 2048, En = 512, Hn = 4, Dn = 128;
constexpr int BHn = Bn * Hn;          // 32
constexpr int Mqkv = Bn * Sn;         // 16384

typedef __attribute__((ext_vector_type(8))) short short8;
typedef __attribute__((ext_vector_type(4))) float f32x4;

__device__ __forceinline__ unsigned short f2bf(float f) {
  unsigned int u = __builtin_bit_cast(unsigned int, f);
  u += 0x7FFF + ((u >> 16) & 1);   // round-to-nearest-even
  return (unsigned short)(u >> 16);
}

// publish LDS writes; do NOT drain vmcnt (prefetch loads stay in flight)
__device__ __forceinline__ void bar_pub() {
  asm volatile("s_waitcnt lgkmcnt(0)" ::: "memory");
  __builtin_amdgcn_s_barrier();
  asm volatile("" ::: "memory");
}

// ---------------------------------------------------------------------------
// K1: QKV projection (unchanged).
// ---------------------------------------------------------------------------
__global__ __launch_bounds__(256) void qkv_kernel(
    const float* __restrict__ x, const float* __restrict__ Wq,
    const float* __restrict__ Wk, const float* __restrict__ Wv,
    const float* __restrict__ bq, const float* __restrict__ bk,
    const float* __restrict__ bv, unsigned short* __restrict__ qkv) {
  const int z = blockIdx.z;
  const float* W = (z == 0) ? Wq : (z == 1 ? Wk : Wv);
  const float* bias = (z == 0) ? bq : (z == 1 ? bk : bv);
  unsigned short* out = qkv + (size_t)z * BHn * Sn * Dn;

  __shared__ unsigned short As[128][40];
  __shared__ unsigned short BsT[128][40];

  const int t = threadIdx.x;
  const int l = t & 63, w = t >> 6;
  const int wm = w >> 1, wn = w & 1;
  const int m0 = blockIdx.x * 128, n0 = blockIdx.y * 128;

  f32x4 acc[4][4] = {};

  for (int k0 = 0; k0 < En; k0 += 32) {
    __syncthreads();
#pragma unroll
    for (int i = 0; i < 4; ++i) {
      int idx = t + i * 256;
      int row = idx >> 3, c4 = (idx & 7) * 4;
      float4 v = *reinterpret_cast<const float4*>(&x[(size_t)(m0 + row) * En + k0 + c4]);
      ushort4 p;
      p.x = f2bf(v.x); p.y = f2bf(v.y); p.z = f2bf(v.z); p.w = f2bf(v.w);
      *reinterpret_cast<ushort4*>(&As[row][c4]) = p;
    }
#pragma unroll
    for (int i = 0; i < 4; ++i) {
      int idx = t + i * 256;
      int kk = idx >> 5, c4 = (idx & 31) * 4;
      float4 v = *reinterpret_cast<const float4*>(&W[(size_t)(k0 + kk) * En + n0 + c4]);
      BsT[c4 + 0][kk] = f2bf(v.x);
      BsT[c4 + 1][kk] = f2bf(v.y);
      BsT[c4 + 2][kk] = f2bf(v.z);
      BsT[c4 + 3][kk] = f2bf(v.w);
    }
    __syncthreads();

    const int koff = (l >> 4) * 8;
    short8 a[4], bfr[4];
#pragma unroll
    for (int m = 0; m < 4; ++m)
      a[m] = *reinterpret_cast<const short8*>(&As[wm * 64 + m * 16 + (l & 15)][koff]);
#pragma unroll
    for (int n = 0; n < 4; ++n)
      bfr[n] = *reinterpret_cast<const short8*>(&BsT[wn * 64 + n * 16 + (l & 15)][koff]);
#pragma unroll
    for (int m = 0; m < 4; ++m)
#pragma unroll
      for (int n = 0; n < 4; ++n)
        acc[m][n] = __builtin_amdgcn_mfma_f32_16x16x32_bf16(a[m], bfr[n], acc[m][n], 0, 0, 0);
  }

#pragma unroll
  for (int m = 0; m < 4; ++m)
#pragma unroll
    for (int n = 0; n < 4; ++n)
#pragma unroll
      for (int j = 0; j < 4; ++j) {
        int row = m0 + wm * 64 + m * 16 + (l >> 4) * 4 + j;
        int col = n0 + wn * 64 + n * 16 + (l & 15);
        int s = row & (Sn - 1);
        float v = acc[m][n][j] + bias[s];
        int b = row >> 11;
        int h = col >> 7, d = col & 127;
        out[(size_t)((b * Hn + h) * Sn + s) * Dn + d] = f2bf(v);
      }
}

// ---------------------------------------------------------------------------
// K1b: V transpose  v[bh][s][d] -> vT[bh][d][s] (unchanged).
// ---------------------------------------------------------------------------
__global__ __launch_bounds__(256) void vtrans_kernel(
    const unsigned short* __restrict__ v, unsigned short* __restrict__ vT) {
  const int s0 = blockIdx.x * 64, d0 = blockIdx.y * 64;
  const int bh = blockIdx.z;
  const unsigned short* vp = v + (size_t)bh * Sn * Dn;
  unsigned short* op = vT + (size_t)bh * Dn * Sn;
  __shared__ unsigned short Ls[64][72];
  const int t = threadIdx.x;
#pragma unroll
  for (int it = 0; it < 2; ++it) {
    int flat = t + it * 256;
    int r = flat >> 3, cc = flat & 7;
    *reinterpret_cast<short8*>(&Ls[r][cc * 8]) =
        *reinterpret_cast<const short8*>(&vp[(size_t)(s0 + r) * Dn + d0 + cc * 8]);
  }
  __syncthreads();
#pragma unroll
  for (int it = 0; it < 2; ++it) {
    int flat = t + it * 256;
    int d = flat >> 3, sc = flat & 7;
    short8 o;
#pragma unroll
    for (int jo = 0; jo < 8; ++jo) {
      int jj = (jo + sc) & 7;
      o[jj] = (short)Ls[sc * 8 + jj][d];
    }
    *reinterpret_cast<short8*>(&op[(size_t)(d0 + d) * Sn + s0 + sc * 8]) = o;
  }
}

// ---------------------------------------------------------------------------
// K2: fused attention v4 — SWAPPED QK^T: acc = mfma(K_frag, Q_frag) so the
// q-row index s is lane-local (s = s0 + w*16 + i).  Consequences:
//   * attn stores & Wepi loads are float4 (4/iter, not 16 scalars)
//   * rinv is one scalar per lane; sweep-1 reduce = 2 shfls total
//   * P staging is per-wave private (no barrier, b64 writes / b128 reads)
//   * Vt double-buffered -> ONE barrier per iteration
// ---------------------------------------------------------------------------
__global__ __launch_bounds__(256, 2) void fused_attn4_kernel(
    const unsigned short* __restrict__ qkv, const unsigned short* __restrict__ vT,
    const float* __restrict__ Wepi, const float* __restrict__ bo,
    float* __restrict__ attn, float* __restrict__ effect) {
  const int bh = blockIdx.y;
  const int s0 = blockIdx.x * 64;
  const unsigned short* qp = qkv + (size_t)bh * Sn * Dn;
  const unsigned short* kp = qkv + (size_t)(BHn + bh) * Sn * Dn;
  const unsigned short* vt = vT + (size_t)bh * Dn * Sn;

  __shared__ unsigned short Kb[2][64 * 128];   // K tiles [t][d], XOR-swizzled
  __shared__ unsigned short Vt[2][128 * 64];   // V^T tiles [d][t], XOR-swizzled
  __shared__ unsigned short Psw[4][16 * 72];   // per-wave P rows [s-local][t]

  const int t = threadIdx.x, l = t & 63, w = t >> 6;
  const int g = l >> 4, i = l & 15;
  const float scale = 0.022097086912079608f;  // 1/sqrt(2048)

  // Q B-frags for rows s0 + w*16 + i (16 VGPR)
  short8 aq[4];
#pragma unroll
  for (int ks = 0; ks < 4; ++ks)
    aq[ks] = *reinterpret_cast<const short8*>(
        &qp[(size_t)(s0 + w * 16 + i) * Dn + ks * 32 + g * 8]);

  // staging descriptors
  int ksrc[4], kdst[4], vsrc[4], vdst[4];
#pragma unroll
  for (int it = 0; it < 4; ++it) {
    int flat = t + it * 256;
    int r = flat >> 4, cc = flat & 15;           // K tile: 64 rows x 16 chunks
    ksrc[it] = r * Dn + cc * 8;
    kdst[it] = r * 128 + ((cc ^ (r & 15)) << 3);
    int d = flat >> 3, ct = flat & 7;            // Vt tile: 128 rows x 8 chunks
    vsrc[it] = d * Sn + ct * 8;
    vdst[it] = d * 64 + ((ct ^ (d & 7)) << 3);
  }

  // ---------------- sweep 1: exp row-sums ----------------
  short8 kreg[4];
#pragma unroll
  for (int it = 0; it < 4; ++it)
    kreg[it] = *reinterpret_cast<const short8*>(&kp[ksrc[it]]);
#pragma unroll
  for (int it = 0; it < 4; ++it)
    *reinterpret_cast<short8*>(&Kb[0][kdst[it]]) = kreg[it];
#pragma unroll
  for (int it = 0; it < 4; ++it)
    kreg[it] = *reinterpret_cast<const short8*>(&kp[(size_t)64 * Dn + ksrc[it]]);
  bar_pub();

  float rs = 0.f;
  for (int kt = 0; kt < 32; ++kt) {
    const int b = kt & 1;
    f32x4 accT[4] = {};
    __builtin_amdgcn_s_setprio(1);
#pragma unroll
    for (int ks = 0; ks < 4; ++ks)
#pragma unroll
      for (int tf = 0; tf < 4; ++tf) {
        short8 ak = *reinterpret_cast<const short8*>(
            &Kb[b][(tf * 16 + i) * 128 + (((ks * 4 + g) ^ i) << 3)]);
        accT[tf] = __builtin_amdgcn_mfma_f32_16x16x32_bf16(ak, aq[ks], accT[tf], 0, 0, 0);
      }
    __builtin_amdgcn_s_setprio(0);
    float p0 = 0.f, p1 = 0.f;
#pragma unroll
    for (int tf = 0; tf < 4; ++tf) {
      p0 += __expf(accT[tf][0] * scale) + __expf(accT[tf][1] * scale);
      p1 += __expf(accT[tf][2] * scale) + __expf(accT[tf][3] * scale);
    }
    rs += p0 + p1;
    if (kt < 31) {
#pragma unroll
      for (int it = 0; it < 4; ++it)
        *reinterpret_cast<short8*>(&Kb[b ^ 1][kdst[it]]) = kreg[it];
      if (kt < 30)
#pragma unroll
        for (int it = 0; it < 4; ++it)
          kreg[it] = *reinterpret_cast<const short8*>(
              &kp[(size_t)(kt + 2) * 64 * Dn + ksrc[it]]);
    }
    bar_pub();
  }
  rs += __shfl_xor(rs, 16);
  rs += __shfl_xor(rs, 32);
  const float rinv = 1.0f / rs;   // per-lane: row s = s0 + w*16 + i

  // ---------------- sweep 2: recompute, write attn, PV ----------------
  short8 vreg[4];
#pragma unroll
  for (int it = 0; it < 4; ++it) {
    kreg[it] = *reinterpret_cast<const short8*>(&kp[ksrc[it]]);
    vreg[it] = *reinterpret_cast<const short8*>(&vt[vsrc[it]]);
  }
#pragma unroll
  for (int it = 0; it < 4; ++it) {
    *reinterpret_cast<short8*>(&Kb[0][kdst[it]]) = kreg[it];
    *reinterpret_cast<short8*>(&Vt[0][vdst[it]]) = vreg[it];
  }
#pragma unroll
  for (int it = 0; it < 4; ++it) {
    kreg[it] = *reinterpret_cast<const short8*>(&kp[(size_t)64 * Dn + ksrc[it]]);
    vreg[it] = *reinterpret_cast<const short8*>(&vt[64 + vsrc[it]]);
  }
  // Wepi row pointer for this lane's q-row; first tile prefetch (float4 x4)
  const float* wrow = Wepi + (size_t)(s0 + w * 16 + i) * Sn + g * 4;
  float4 wr[4];
#pragma unroll
  for (int tf = 0; tf < 4; ++tf)
    wr[tf] = *reinterpret_cast<const float4*>(&wrow[tf * 16]);
  bar_pub();

  f32x4 pv[8] = {};
  float* arow = attn + (size_t)bh * Sn * Sn + (size_t)(s0 + w * 16 + i) * Sn;

  for (int kt = 0; kt < 32; ++kt) {
    const int b = kt & 1;
    const int t0 = kt * 64;
    f32x4 accT[4] = {};
    __builtin_amdgcn_s_setprio(1);
#pragma unroll
    for (int ks = 0; ks < 4; ++ks)
#pragma unroll
      for (int tf = 0; tf < 4; ++tf) {
        short8 ak = *reinterpret_cast<const short8*>(
            &Kb[b][(tf * 16 + i) * 128 + (((ks * 4 + g) ^ i) << 3)]);
        accT[tf] = __builtin_amdgcn_mfma_f32_16x16x32_bf16(ak, aq[ks], accT[tf], 0, 0, 0);
      }
    __builtin_amdgcn_s_setprio(0);

    // issue next tile's Wepi loads early (consumed next iteration)
    float4 nwr[4];
    if (kt < 31)
#pragma unroll
      for (int tf = 0; tf < 4; ++tf)
        nwr[tf] = *reinterpret_cast<const float4*>(&wrow[t0 + 64 + tf * 16]);

    // epilogue: p = exp*rinv*Wepi -> attn float4 store + per-wave Ps (b64)
#pragma unroll
    for (int tf = 0; tf < 4; ++tf) {
      float q0 = __expf(accT[tf][0] * scale) * rinv * wr[tf].x;
      float q1 = __expf(accT[tf][1] * scale) * rinv * wr[tf].y;
      float q2 = __expf(accT[tf][2] * scale) * rinv * wr[tf].z;
      float q3 = __expf(accT[tf][3] * scale) * rinv * wr[tf].w;
      float4 pf4 = {q0, q1, q2, q3};
      *reinterpret_cast<float4*>(&arow[t0 + tf * 16 + g * 4]) = pf4;
      ushort4 pk;
      pk.x = f2bf(q0); pk.y = f2bf(q1); pk.z = f2bf(q2); pk.w = f2bf(q3);
      *reinterpret_cast<ushort4*>(&Psw[w][i * 72 + tf * 16 + g * 4]) = pk;
    }

    // PV: A = Psw rows (per-wave, no barrier), B = Vt[b]
    __builtin_amdgcn_s_setprio(1);
#pragma unroll
    for (int ks2 = 0; ks2 < 2; ++ks2) {
      short8 pa = *reinterpret_cast<const short8*>(&Psw[w][i * 72 + ks2 * 32 + g * 8]);
#pragma unroll
      for (int df = 0; df < 8; ++df) {
        const int d = df * 16 + i;
        short8 bv = *reinterpret_cast<const short8*>(
            &Vt[b][d * 64 + (((ks2 * 4 + g) ^ (d & 7)) << 3)]);
        pv[df] = __builtin_amdgcn_mfma_f32_16x16x32_bf16(pa, bv, pv[df], 0, 0, 0);
      }
    }
    __builtin_amdgcn_s_setprio(0);

    // stage next K/Vt into the idle buffers; issue loads for kt+2
    if (kt < 31) {
#pragma unroll
      for (int it = 0; it < 4; ++it) {
        *reinterpret_cast<short8*>(&Kb[b ^ 1][kdst[it]]) = kreg[it];
        *reinterpret_cast<short8*>(&Vt[b ^ 1][vdst[it]]) = vreg[it];
      }
      if (kt < 30)
#pragma unroll
        for (int it = 0; it < 4; ++it) {
          kreg[it] = *reinterpret_cast<const short8*>(
              &kp[(size_t)(t0 + 128) * Dn + ksrc[it]]);
          vreg[it] = *reinterpret_cast<const short8*>(&vt[t0 + 128 + vsrc[it]]);
        }
#pragma unroll
      for (int tf = 0; tf < 4; ++tf) wr[tf] = nwr[tf];
    }
    bar_pub();
  }

  // effect = pv + bo   (row s = s0 + w*16 + g*4 + j, col d = df*16 + i)
  const int b_ = bh >> 2, h_ = bh & 3;
#pragma unroll
  for (int j = 0; j < 4; ++j) {
    const int row = s0 + w * 16 + g * 4 + j;
    const float bias = bo[row];
#pragma unroll
    for (int df = 0; df < 8; ++df)
      effect[(size_t)(b_ * Sn + row) * En + h_ * Dn + df * 16 + i] = pv[df][j] + bias;
  }
}

// ---------------------------------------------------------------------------
extern "C" void kernel_launch(void* const* d_in, const int* in_sizes, int n_in,
                              void* d_out, int out_size, void* d_ws, size_t ws_size,
                              hipStream_t stream) {
  const float* x    = (const float*)d_in[0];
  const float* Wq   = (const float*)d_in[1];
  const float* Wk   = (const float*)d_in[2];
  const float* Wv   = (const float*)d_in[3];
  const float* Wepi = (const float*)d_in[4];
  const float* bq   = (const float*)d_in[5];
  const float* bk   = (const float*)d_in[6];
  const float* bv   = (const float*)d_in[7];
  const float* bo   = (const float*)d_in[8];

  float* effect = (float*)d_out;
  float* attn = effect + (size_t)Bn * Sn * En;              // attn region of d_out
  unsigned short* qkv = (unsigned short*)d_ws;              // q|k|v bf16 (50.3 MB)
  unsigned short* vT = qkv + (size_t)3 * BHn * Sn * Dn;     // v^T bf16 (16.8 MB)

  qkv_kernel<<<dim3(Mqkv / 128, En / 128, 3), 256, 0, stream>>>(x, Wq, Wk, Wv, bq, bk, bv, qkv);
  vtrans_kernel<<<dim3(Sn / 64, Dn / 64, BHn), 256, 0, stream>>>(
      qkv + (size_t)2 * BHn * Sn * Dn, vT);
  fused_attn4_kernel<<<dim3(Sn / 64, BHn), 256, 0, stream>>>(qkv, vT, Wepi, bo, attn, effect);
}

// Round 6
// 406.498 us; speedup vs baseline: 1.0114x; 1.0114x over previous
//
#include <hip/hip_runtime.h>
#include <hip/hip_bf16.h>

// Problem constants
constexpr int Bn = 8, Sn = 2048, En = 512, Hn = 4, Dn = 128;
constexpr int BHn = Bn * Hn;          // 32
constexpr int Mqkv = Bn * Sn;         // 16384

typedef __attribute__((ext_vector_type(8))) short short8;
typedef __attribute__((ext_vector_type(4))) float f32x4;

__device__ __forceinline__ unsigned short f2bf(float f) {
  unsigned int u = __builtin_bit_cast(unsigned int, f);
  u += 0x7FFF + ((u >> 16) & 1);   // round-to-nearest-even
  return (unsigned short)(u >> 16);
}

// publish LDS writes; do NOT drain vmcnt (prefetch loads stay in flight)
__device__ __forceinline__ void bar_pub() {
  asm volatile("s_waitcnt lgkmcnt(0)" ::: "memory");
  __builtin_amdgcn_s_barrier();
  asm volatile("" ::: "memory");
}

// ---------------------------------------------------------------------------
// K1: QKV projection (unchanged).
// ---------------------------------------------------------------------------
__global__ __launch_bounds__(256) void qkv_kernel(
    const float* __restrict__ x, const float* __restrict__ Wq,
    const float* __restrict__ Wk, const float* __restrict__ Wv,
    const float* __restrict__ bq, const float* __restrict__ bk,
    const float* __restrict__ bv, unsigned short* __restrict__ qkv) {
  const int z = blockIdx.z;
  const float* W = (z == 0) ? Wq : (z == 1 ? Wk : Wv);
  const float* bias = (z == 0) ? bq : (z == 1 ? bk : bv);
  unsigned short* out = qkv + (size_t)z * BHn * Sn * Dn;

  __shared__ unsigned short As[128][40];
  __shared__ unsigned short BsT[128][40];

  const int t = threadIdx.x;
  const int l = t & 63, w = t >> 6;
  const int wm = w >> 1, wn = w & 1;
  const int m0 = blockIdx.x * 128, n0 = blockIdx.y * 128;

  f32x4 acc[4][4] = {};

  for (int k0 = 0; k0 < En; k0 += 32) {
    __syncthreads();
#pragma unroll
    for (int i = 0; i < 4; ++i) {
      int idx = t + i * 256;
      int row = idx >> 3, c4 = (idx & 7) * 4;
      float4 v = *reinterpret_cast<const float4*>(&x[(size_t)(m0 + row) * En + k0 + c4]);
      ushort4 p;
      p.x = f2bf(v.x); p.y = f2bf(v.y); p.z = f2bf(v.z); p.w = f2bf(v.w);
      *reinterpret_cast<ushort4*>(&As[row][c4]) = p;
    }
#pragma unroll
    for (int i = 0; i < 4; ++i) {
      int idx = t + i * 256;
      int kk = idx >> 5, c4 = (idx & 31) * 4;
      float4 v = *reinterpret_cast<const float4*>(&W[(size_t)(k0 + kk) * En + n0 + c4]);
      BsT[c4 + 0][kk] = f2bf(v.x);
      BsT[c4 + 1][kk] = f2bf(v.y);
      BsT[c4 + 2][kk] = f2bf(v.z);
      BsT[c4 + 3][kk] = f2bf(v.w);
    }
    __syncthreads();

    const int koff = (l >> 4) * 8;
    short8 a[4], bfr[4];
#pragma unroll
    for (int m = 0; m < 4; ++m)
      a[m] = *reinterpret_cast<const short8*>(&As[wm * 64 + m * 16 + (l & 15)][koff]);
#pragma unroll
    for (int n = 0; n < 4; ++n)
      bfr[n] = *reinterpret_cast<const short8*>(&BsT[wn * 64 + n * 16 + (l & 15)][koff]);
#pragma unroll
    for (int m = 0; m < 4; ++m)
#pragma unroll
      for (int n = 0; n < 4; ++n)
        acc[m][n] = __builtin_amdgcn_mfma_f32_16x16x32_bf16(a[m], bfr[n], acc[m][n], 0, 0, 0);
  }

#pragma unroll
  for (int m = 0; m < 4; ++m)
#pragma unroll
    for (int n = 0; n < 4; ++n)
#pragma unroll
      for (int j = 0; j < 4; ++j) {
        int row = m0 + wm * 64 + m * 16 + (l >> 4) * 4 + j;
        int col = n0 + wn * 64 + n * 16 + (l & 15);
        int s = row & (Sn - 1);
        float v = acc[m][n][j] + bias[s];
        int b = row >> 11;
        int h = col >> 7, d = col & 127;
        out[(size_t)((b * Hn + h) * Sn + s) * Dn + d] = f2bf(v);
      }
}

// ---------------------------------------------------------------------------
// K1b: V transpose  v[bh][s][d] -> vT[bh][d][s] (unchanged).
// ---------------------------------------------------------------------------
__global__ __launch_bounds__(256) void vtrans_kernel(
    const unsigned short* __restrict__ v, unsigned short* __restrict__ vT) {
  const int s0 = blockIdx.x * 64, d0 = blockIdx.y * 64;
  const int bh = blockIdx.z;
  const unsigned short* vp = v + (size_t)bh * Sn * Dn;
  unsigned short* op = vT + (size_t)bh * Dn * Sn;
  __shared__ unsigned short Ls[64][72];
  const int t = threadIdx.x;
#pragma unroll
  for (int it = 0; it < 2; ++it) {
    int flat = t + it * 256;
    int r = flat >> 3, cc = flat & 7;
    *reinterpret_cast<short8*>(&Ls[r][cc * 8]) =
        *reinterpret_cast<const short8*>(&vp[(size_t)(s0 + r) * Dn + d0 + cc * 8]);
  }
  __syncthreads();
#pragma unroll
  for (int it = 0; it < 2; ++it) {
    int flat = t + it * 256;
    int d = flat >> 3, sc = flat & 7;
    short8 o;
#pragma unroll
    for (int jo = 0; jo < 8; ++jo) {
      int jj = (jo + sc) & 7;
      o[jj] = (short)Ls[sc * 8 + jj][d];
    }
    *reinterpret_cast<short8*>(&op[(size_t)(d0 + d) * Sn + s0 + sc * 8]) = o;
  }
}

// ---------------------------------------------------------------------------
// K2: fused attention v5 — wave-disjoint LDS partition + 1-barrier pipeline.
// QK^T: A = K rows (wave owns 16 t-rows -> 4 LDS reads/iter), B = Q in regs
//       (all 64 s-rows, 64 VGPR).  C[t][s], s = lane i (lane-local).
// PV (lags one iter): A = P rows (8 reads), B = Vt cols (wave owns 32 d ->
//       4 reads).  Everything double-buffered; one barrier per iteration.
// ---------------------------------------------------------------------------
__global__ __launch_bounds__(256, 2) void fused_attn5_kernel(
    const unsigned short* __restrict__ qkv, const unsigned short* __restrict__ vT,
    const float* __restrict__ Wepi, const float* __restrict__ bo,
    float* __restrict__ attn, float* __restrict__ effect) {
  const int bh = blockIdx.y;
  const int s0 = blockIdx.x * 64;
  const unsigned short* qp = qkv + (size_t)bh * Sn * Dn;
  const unsigned short* kp = qkv + (size_t)(BHn + bh) * Sn * Dn;
  const unsigned short* vt = vT + (size_t)bh * Dn * Sn;

  __shared__ unsigned short Kb[2][64 * 128];   // K tiles [t][d], XOR-swizzled
  __shared__ unsigned short Vt[2][128 * 64];   // V^T tiles [d][t], XOR-swizzled
  __shared__ unsigned short Ps[2][64 * 64];    // P tiles [s][t], XOR-swizzled

  const int t = threadIdx.x, l = t & 63, w = t >> 6;
  const int g = l >> 4, i = l & 15;
  const float scale = 0.022097086912079608f;  // 1/sqrt(2048)

  // Q B-frags for ALL 64 q-rows: aq[sf][ks] (64 VGPR)
  short8 aq[4][4];
#pragma unroll
  for (int sf = 0; sf < 4; ++sf)
#pragma unroll
    for (int ks = 0; ks < 4; ++ks)
      aq[sf][ks] = *reinterpret_cast<const short8*>(
          &qp[(size_t)(s0 + sf * 16 + i) * Dn + ks * 32 + g * 8]);

  // staging descriptors
  int ksrc[4], kdst[4], vsrc[4], vdst[4];
#pragma unroll
  for (int it = 0; it < 4; ++it) {
    int flat = t + it * 256;
    int r = flat >> 4, cc = flat & 15;           // K tile: 64 rows x 16 chunks
    ksrc[it] = r * Dn + cc * 8;
    kdst[it] = r * 128 + ((cc ^ (r & 15)) << 3);
    int d = flat >> 3, ct = flat & 7;            // Vt tile: 128 rows x 8 chunks
    vsrc[it] = d * Sn + ct * 8;
    vdst[it] = d * 64 + ((ct ^ (d & 7)) << 3);
  }

  // ---------------- sweep 1: exp row-sums ----------------
  short8 kreg[4];
#pragma unroll
  for (int it = 0; it < 4; ++it)
    kreg[it] = *reinterpret_cast<const short8*>(&kp[ksrc[it]]);
#pragma unroll
  for (int it = 0; it < 4; ++it)
    *reinterpret_cast<short8*>(&Kb[0][kdst[it]]) = kreg[it];
#pragma unroll
  for (int it = 0; it < 4; ++it)
    kreg[it] = *reinterpret_cast<const short8*>(&kp[(size_t)64 * Dn + ksrc[it]]);
  bar_pub();

  float rs[4] = {0.f, 0.f, 0.f, 0.f};
  for (int kt = 0; kt < 32; ++kt) {
    const int b = kt & 1;
    f32x4 accT[4] = {};
    __builtin_amdgcn_s_setprio(1);
#pragma unroll
    for (int ks = 0; ks < 4; ++ks) {
      short8 ak = *reinterpret_cast<const short8*>(
          &Kb[b][(w * 16 + i) * 128 + (((ks * 4 + g) ^ i) << 3)]);
#pragma unroll
      for (int sf = 0; sf < 4; ++sf)
        accT[sf] = __builtin_amdgcn_mfma_f32_16x16x32_bf16(ak, aq[sf][ks], accT[sf], 0, 0, 0);
    }
    __builtin_amdgcn_s_setprio(0);
#pragma unroll
    for (int sf = 0; sf < 4; ++sf)
      rs[sf] += __expf(accT[sf][0] * scale) + __expf(accT[sf][1] * scale) +
                __expf(accT[sf][2] * scale) + __expf(accT[sf][3] * scale);
    if (kt < 31) {
#pragma unroll
      for (int it = 0; it < 4; ++it)
        *reinterpret_cast<short8*>(&Kb[b ^ 1][kdst[it]]) = kreg[it];
      if (kt < 30)
#pragma unroll
        for (int it = 0; it < 4; ++it)
          kreg[it] = *reinterpret_cast<const short8*>(
              &kp[(size_t)(kt + 2) * 64 * Dn + ksrc[it]]);
    }
    bar_pub();
  }

  // reduce: over g-groups in-wave, over waves via LDS (overlaid on Ps[0])
  float* wpart = reinterpret_cast<float*>(&Ps[0][0]);   // [4][64] floats
#pragma unroll
  for (int sf = 0; sf < 4; ++sf) {
    float v = rs[sf];
    v += __shfl_xor(v, 16);
    v += __shfl_xor(v, 32);
    if (l < 16) wpart[w * 64 + sf * 16 + l] = v;
  }
  bar_pub();
  float rinv[4];
#pragma unroll
  for (int sf = 0; sf < 4; ++sf) {
    const int s = sf * 16 + i;
    rinv[sf] = 1.0f / (wpart[s] + wpart[64 + s] + wpart[128 + s] + wpart[192 + s]);
  }

  // ---------------- sweep 2 prologue ----------------
  short8 vreg[4];
#pragma unroll
  for (int it = 0; it < 4; ++it)
    kreg[it] = *reinterpret_cast<const short8*>(&kp[ksrc[it]]);
#pragma unroll
  for (int it = 0; it < 4; ++it)
    *reinterpret_cast<short8*>(&Kb[0][kdst[it]]) = kreg[it];
#pragma unroll
  for (int it = 0; it < 4; ++it) {
    kreg[it] = *reinterpret_cast<const short8*>(&kp[(size_t)64 * Dn + ksrc[it]]);
    vreg[it] = *reinterpret_cast<const short8*>(&vt[vsrc[it]]);
  }
  const float* wbase = Wepi + (size_t)(s0 + i) * Sn + w * 16 + g * 4;
  float* abase = attn + (size_t)bh * Sn * Sn + (size_t)(s0 + i) * Sn + w * 16 + g * 4;
  float4 wr[4];
#pragma unroll
  for (int sf = 0; sf < 4; ++sf)
    wr[sf] = *reinterpret_cast<const float4*>(&wbase[(size_t)sf * 16 * Sn]);
  bar_pub();   // publishes Kb[0]; all rinv LDS reads retired block-wide

  // ---------------- sweep 2 main loop (PV lags by 1) ----------------
  f32x4 pv[4][2] = {};
  for (int kt = 0; kt < 32; ++kt) {
    const int b = kt & 1;
    const int t0 = kt * 64;
    f32x4 accT[4] = {};
    __builtin_amdgcn_s_setprio(1);
#pragma unroll
    for (int ks = 0; ks < 4; ++ks) {
      short8 ak = *reinterpret_cast<const short8*>(
          &Kb[b][(w * 16 + i) * 128 + (((ks * 4 + g) ^ i) << 3)]);
#pragma unroll
      for (int sf = 0; sf < 4; ++sf)
        accT[sf] = __builtin_amdgcn_mfma_f32_16x16x32_bf16(ak, aq[sf][ks], accT[sf], 0, 0, 0);
    }
    // PV for tile kt-1 (reads Ps[b^1], Vt[b^1])
    if (kt > 0) {
#pragma unroll
      for (int ks2 = 0; ks2 < 2; ++ks2) {
        short8 pa[4];
#pragma unroll
        for (int sf = 0; sf < 4; ++sf)
          pa[sf] = *reinterpret_cast<const short8*>(
              &Ps[b ^ 1][(sf * 16 + i) * 64 + (((ks2 * 4 + g) ^ (i & 7)) << 3)]);
#pragma unroll
        for (int nf = 0; nf < 2; ++nf) {
          const int d = w * 32 + nf * 16 + i;
          short8 bv = *reinterpret_cast<const short8*>(
              &Vt[b ^ 1][d * 64 + (((ks2 * 4 + g) ^ (i & 7)) << 3)]);
#pragma unroll
          for (int sf = 0; sf < 4; ++sf)
            pv[sf][nf] =
                __builtin_amdgcn_mfma_f32_16x16x32_bf16(pa[sf], bv, pv[sf][nf], 0, 0, 0);
        }
      }
    }
    __builtin_amdgcn_s_setprio(0);

    // epilogue: p = exp*rinv*Wepi -> attn float4 store + Ps[b] ushort4 write
#pragma unroll
    for (int sf = 0; sf < 4; ++sf) {
      float q0 = __expf(accT[sf][0] * scale) * rinv[sf] * wr[sf].x;
      float q1 = __expf(accT[sf][1] * scale) * rinv[sf] * wr[sf].y;
      float q2 = __expf(accT[sf][2] * scale) * rinv[sf] * wr[sf].z;
      float q3 = __expf(accT[sf][3] * scale) * rinv[sf] * wr[sf].w;
      float4 pf4 = {q0, q1, q2, q3};
      *reinterpret_cast<float4*>(&abase[(size_t)sf * 16 * Sn + t0]) = pf4;
      ushort4 pk;
      pk.x = f2bf(q0); pk.y = f2bf(q1); pk.z = f2bf(q2); pk.w = f2bf(q3);
      const int row = sf * 16 + i;
      *reinterpret_cast<ushort4*>(
          &Ps[b][row * 64 + (((w * 2 + (g >> 1)) ^ (i & 7)) << 3) + (g & 1) * 4]) = pk;
    }
    // reload Wepi for next tile (post-use; covered by next iteration)
    if (kt < 31)
#pragma unroll
      for (int sf = 0; sf < 4; ++sf)
        wr[sf] = *reinterpret_cast<const float4*>(&wbase[(size_t)sf * 16 * Sn + t0 + 64]);

    // stage next tiles into idle buffers; prefetch globals
    if (kt < 31)
#pragma unroll
      for (int it = 0; it < 4; ++it)
        *reinterpret_cast<short8*>(&Kb[b ^ 1][kdst[it]]) = kreg[it];
#pragma unroll
    for (int it = 0; it < 4; ++it)
      *reinterpret_cast<short8*>(&Vt[b][vdst[it]]) = vreg[it];
    if (kt < 30)
#pragma unroll
      for (int it = 0; it < 4; ++it)
        kreg[it] = *reinterpret_cast<const short8*>(
            &kp[(size_t)(kt + 2) * 64 * Dn + ksrc[it]]);
    if (kt < 31)
#pragma unroll
      for (int it = 0; it < 4; ++it)
        vreg[it] = *reinterpret_cast<const short8*>(&vt[t0 + 64 + vsrc[it]]);
    bar_pub();
  }

  // final PV for tile 31 (Ps[1], Vt[1] — published by the last barrier)
  __builtin_amdgcn_s_setprio(1);
#pragma unroll
  for (int ks2 = 0; ks2 < 2; ++ks2) {
    short8 pa[4];
#pragma unroll
    for (int sf = 0; sf < 4; ++sf)
      pa[sf] = *reinterpret_cast<const short8*>(
          &Ps[1][(sf * 16 + i) * 64 + (((ks2 * 4 + g) ^ (i & 7)) << 3)]);
#pragma unroll
    for (int nf = 0; nf < 2; ++nf) {
      const int d = w * 32 + nf * 16 + i;
      short8 bv = *reinterpret_cast<const short8*>(
          &Vt[1][d * 64 + (((ks2 * 4 + g) ^ (i & 7)) << 3)]);
#pragma unroll
      for (int sf = 0; sf < 4; ++sf)
        pv[sf][nf] = __builtin_amdgcn_mfma_f32_16x16x32_bf16(pa[sf], bv, pv[sf][nf], 0, 0, 0);
    }
  }
  __builtin_amdgcn_s_setprio(0);

  // effect = pv + bo : row s = s0+sf*16+g*4+j, col d = w*32+nf*16+i
  const int b_ = bh >> 2, h_ = bh & 3;
#pragma unroll
  for (int sf = 0; sf < 4; ++sf)
#pragma unroll
    for (int j = 0; j < 4; ++j) {
      const int row = s0 + sf * 16 + g * 4 + j;
      const float bias = bo[row];
#pragma unroll
      for (int nf = 0; nf < 2; ++nf)
        effect[(size_t)(b_ * Sn + row) * En + h_ * Dn + w * 32 + nf * 16 + i] =
            pv[sf][nf][j] + bias;
    }
}

// ---------------------------------------------------------------------------
extern "C" void kernel_launch(void* const* d_in, const int* in_sizes, int n_in,
                              void* d_out, int out_size, void* d_ws, size_t ws_size,
                              hipStream_t stream) {
  const float* x    = (const float*)d_in[0];
  const float* Wq   = (const float*)d_in[1];
  const float* Wk   = (const float*)d_in[2];
  const float* Wv   = (const float*)d_in[3];
  const float* Wepi = (const float*)d_in[4];
  const float* bq   = (const float*)d_in[5];
  const float* bk   = (const float*)d_in[6];
  const float* bv   = (const float*)d_in[7];
  const float* bo   = (const float*)d_in[8];

  float* effect = (float*)d_out;
  float* attn = effect + (size_t)Bn * Sn * En;              // attn region of d_out
  unsigned short* qkv = (unsigned short*)d_ws;              // q|k|v bf16 (50.3 MB)
  unsigned short* vT = qkv + (size_t)3 * BHn * Sn * Dn;     // v^T bf16 (16.8 MB)

  qkv_kernel<<<dim3(Mqkv / 128, En / 128, 3), 256, 0, stream>>>(x, Wq, Wk, Wv, bq, bk, bv, qkv);
  vtrans_kernel<<<dim3(Sn / 64, Dn / 64, BHn), 256, 0, stream>>>(
      qkv + (size_t)2 * BHn * Sn * Dn, vT);
  fused_attn5_kernel<<<dim3(Sn / 64, BHn), 256, 0, stream>>>(qkv, vT, Wepi, bo, attn, effect);
}